// Round 18
// baseline (548.685 us; speedup 1.0000x reference)
//
#include <hip/hip_runtime.h>
#include <math.h>

// ---------------------------------------------------------------------------
// CrossGroupedQueryAttention on MI355X — round 18
//
// R17 post-mortem: 540us best. q-proj still 164us @1.25TB/s, VGPR STILL 64
// -> the 48-load batch never actually went deep (allocator holds ~12).
// Occ 40% = 1.6 blk/CU (LDS 57.8KB).
// R18 (gemm_fused only): (1) phase-1 staged as 3 ping-pong groups of 16
// floats (16-deep MLP that FITS the 64-80 reg budget); (2) LDS -> 52KB
// (float2 stats, muL/sdL aliased into dead sred space — combine is exactly
// wave0, lockstep reads-before-writes; epilogue chunked 2x192 rows) ->
// 3 blocks/CU. Decision rule: if q >= 155us, the NCHW-strided ~1.2-1.8TB/s
// floor is confirmed and next round declares the practical ceiling.
// ---------------------------------------------------------------------------

typedef unsigned short u16;
typedef unsigned int u32;
typedef short s16x8 __attribute__((ext_vector_type(8)));
typedef float f32x4 __attribute__((ext_vector_type(4)));

#define HW 16384
#define NB 8
#define CDIM 384
#define KVC 192

__device__ __forceinline__ float b2f(u16 u) {
  return __uint_as_float(((u32)u) << 16);
}
__device__ __forceinline__ u16 f2b(float f) {
  u32 u = __float_as_uint(f);
  u += 0x7fffu + ((u >> 16) & 1u);   // RNE
  return (u16)(u >> 16);
}
__device__ __forceinline__ u32 pack2(float a, float c) {
  return (u32)f2b(a) | ((u32)f2b(c) << 16);
}

// ---------------------------------------------------------------------------
// k0: fold LN weights. 5 blocks x 256. wkvp zero-padded to 384 rows.
// ---------------------------------------------------------------------------
__global__ void k0_prep(const float* __restrict__ wq, const float* __restrict__ wkv,
                        const float* __restrict__ wo,
                        const float* __restrict__ lnqw, const float* __restrict__ lnqb,
                        const float* __restrict__ lnkw, const float* __restrict__ lnkb,
                        u16* __restrict__ wqp, float* __restrict__ rwsQ, float* __restrict__ biasQ,
                        u16* __restrict__ wkvp, float* __restrict__ rwsKV, float* __restrict__ biasKV,
                        u16* __restrict__ wop) {
  int r = blockIdx.x * 256 + threadIdx.x;
  if (r < 384) {
    float rs = 0.f, bs = 0.f;
    for (int i = 0; i < 384; ++i) {
      float wp = wq[r * 384 + i] * lnqw[i];
      u16 h = f2b(wp);
      rs += b2f(h);
      bs += wq[r * 384 + i] * lnqb[i];
      wqp[r * 384 + i] = h;
    }
    rwsQ[r] = rs; biasQ[r] = bs;
  } else if (r < 768) {
    int o = r - 384;
    if (o < 192) {
      float rs = 0.f, bs = 0.f;
      for (int i = 0; i < 384; ++i) {
        float wp = wkv[o * 384 + i] * lnkw[i];
        u16 h = f2b(wp);
        rs += b2f(h);
        bs += wkv[o * 384 + i] * lnkb[i];
        wkvp[o * 384 + i] = h;
      }
      rwsKV[o] = rs; biasKV[o] = bs;
    } else {
      for (int i = 0; i < 384; ++i) wkvp[o * 384 + i] = 0;
      rwsKV[o] = 0.f; biasKV[o] = 0.f;
    }
  } else if (r < 1152) {
    int o = r - 768;
    for (int i = 0; i < 384; ++i) wop[o * 384 + i] = f2b(wo[o * 384 + i]);
  }
}

// ---------------------------------------------------------------------------
// gemm_fused: D[o][p]=sum_k A[o][k]*B[p][k], K=384, tile M x 64px, 512 thr.
// Phase1: 3 ping-pong groups of 16 f32 loads (16-deep MLP, reg-feasible),
//   cvt + LN stats (float2 sred) -> 48KB swizzled LDS.
// Phase2: A direct from L2 ping-pong, 12 K-steps.
// Epilogue: LN + LDS transpose, chunks of 192 rows, 128B segments.
// smem 53248 B (52KB) -> 3 blocks/CU. muL/sdL alias dead sred (combine is
// wave0-lockstep: reads of all 8 groups precede the aliased writes).
// ---------------------------------------------------------------------------
template <int MODE, int WM, int WN, int MF, int NF>
__global__ __launch_bounds__(512, 4) void gemm_fused(const u16* __restrict__ A,
                                                     const void* __restrict__ Bsrc,
                                                     const float* __restrict__ rowsum,
                                                     const float* __restrict__ bias,
                                                     void* __restrict__ outv, int M) {
  __shared__ __align__(16) char smem[53248];
  u16*    tB   = (u16*)smem;                   // 64 x 384 u16 = 48 KB
  float2* sred = (float2*)(smem + 49152);      // [8][64] = 4 KB
  float*  muL  = (float*)(smem + 49152);       // aliases sred[0..31] (float2)
  float*  sdL  = (float*)(smem + 49408);       // aliases sred[32..63]
  u16*    chB16 = (u16*)smem;                  // epilogue: [192][72] u16 = 27.6KB

  constexpr int M_TILE = WM * MF * 16;
  constexpr int NCHUNK = (M_TILE > 192) ? 2 : 1;

  const int b = blockIdx.z;
  const int pt = ((blockIdx.x & 7) << 5) | (blockIdx.x >> 3);   // XCD-bijective
  const int tid = threadIdx.x;
  const int w = tid >> 6, l = tid & 63;
  const int wm = (WN == 1) ? w : (w >> 1);
  const int wn = (WN == 1) ? 0 : (w & 1);
  const int lr = l & 15, lg = l >> 4;

  f32x4 acc[MF][NF] = {};

  // ================= Phase 1: pipelined group staging =================
  {
    const float* Bf = (const float*)Bsrc;
    const size_t fbase = (size_t)b * CDIM * HW + (size_t)pt * 64 + l;  // lane=px
    float v[2][16];
    float s_ = 0.f, q_ = 0.f;

    // group g covers it = 4g..4g+3 (ch = it*32 + w*4 + j)
#pragma unroll
    for (int m = 0; m < 16; ++m)
      v[0][m] = Bf[fbase + (size_t)((m >> 2) * 32 + w * 4 + (m & 3)) * HW];

#pragma unroll
    for (int g = 0; g < 3; ++g) {
      const int cur = g & 1, nxt = cur ^ 1;
      if (g < 2) {
#pragma unroll
        for (int m = 0; m < 16; ++m)
          v[nxt][m] = Bf[fbase + (size_t)((4 * (g + 1) + (m >> 2)) * 32 + w * 4 + (m & 3)) * HW];
      }
#pragma unroll
      for (int it2 = 0; it2 < 4; ++it2) {
        const int it = 4 * g + it2;
        float v0 = v[cur][it2 * 4], v1 = v[cur][it2 * 4 + 1];
        float v2 = v[cur][it2 * 4 + 2], v3 = v[cur][it2 * 4 + 3];
        s_ += (v0 + v1) + (v2 + v3);
        q_ += (v0 * v0 + v1 * v1) + (v2 * v2 + v3 * v3);
        u32 lo = pack2(v0, v1), hi = pack2(v2, v3);
        int cidx = it * 4 + (w >> 1);
        int off = l * 384 + ((cidx ^ (l & 7)) << 3) + (w & 1) * 4;
        *(uint2*)&tB[off] = make_uint2(lo, hi);
      }
    }
    sred[w * 64 + l] = make_float2(s_, q_);
  }
  __syncthreads();

  // stats combine: exactly wave 0 (lockstep: all reads precede aliased writes)
  if (tid < 64) {
    float s = 0.f, q2 = 0.f;
#pragma unroll
    for (int g = 0; g < 8; ++g) { float2 t = sred[g * 64 + tid]; s += t.x; q2 += t.y; }
    float mn = s * (1.f / 384.f);
    float var = q2 * (1.f / 384.f) - mn * mn;
    muL[tid] = mn;                 // aliases sred — safe, see header comment
    sdL[tid] = rsqrtf(var + 1e-5f);
  }
  __syncthreads();

  // ================= Phase 2: MFMA, ping-pong prefetch =================
  s16x8 a[2][MF], bb[2][NF];
#pragma unroll
  for (int mf = 0; mf < MF; ++mf)
    a[0][mf] = *(const s16x8*)(A + (size_t)(wm * (MF * 16) + mf * 16 + lr) * 384 + lg * 8);
#pragma unroll
  for (int nf = 0; nf < NF; ++nf) {
    int row = wn * (NF * 16) + nf * 16 + lr;
    bb[0][nf] = *(const s16x8*)&tB[row * 384 + ((lg ^ (row & 7)) << 3)];
  }
#pragma unroll
  for (int ks = 0; ks < 12; ++ks) {
    const int cur = ks & 1, nxt = cur ^ 1;
    if (ks < 11) {
      const int ko = (ks + 1) * 32 + lg * 8;
      const int cidx = (ks + 1) * 4 + lg;
#pragma unroll
      for (int mf = 0; mf < MF; ++mf)
        a[nxt][mf] = *(const s16x8*)(A + (size_t)(wm * (MF * 16) + mf * 16 + lr) * 384 + ko);
#pragma unroll
      for (int nf = 0; nf < NF; ++nf) {
        int row = wn * (NF * 16) + nf * 16 + lr;
        bb[nxt][nf] = *(const s16x8*)&tB[row * 384 + ((cidx ^ (row & 7)) << 3)];
      }
    }
#pragma unroll
    for (int mf = 0; mf < MF; ++mf)
#pragma unroll
      for (int nf = 0; nf < NF; ++nf)
        acc[mf][nf] = __builtin_amdgcn_mfma_f32_16x16x32_bf16(a[cur][mf], bb[cur][nf], acc[mf][nf], 0, 0, 0);
  }

  // ================= Epilogue: chunks of 192 rows, 128B segments ==========
#pragma unroll
  for (int cc = 0; cc < NCHUNK; ++cc) {
    __syncthreads();
    if ((wm >> 2) == cc) {
#pragma unroll
      for (int nf = 0; nf < NF; ++nf) {
        int prow = wn * (NF * 16) + nf * 16 + lr;
        float m_ = muL[prow], s_ = sdL[prow];
#pragma unroll
        for (int mf = 0; mf < MF; ++mf)
#pragma unroll
          for (int r = 0; r < 4; ++r) {
            int orow = wm * (MF * 16) + mf * 16 + lg * 4 + r;
            float vv = s_ * (acc[mf][nf][r] - m_ * rowsum[orow]) + bias[orow];
            chB16[((wm & 3) * (MF * 16) + mf * 16 + lg * 4 + r) * 72 + prow] = f2b(vv);
          }
      }
    }
    __syncthreads();
    const int rows = (M_TILE > 192) ? 192 : M_TILE;
    for (int i = tid; i < rows * 8; i += 512) {
      int row = i >> 3, c8 = i & 7;
      int g = cc * 192 + row;
      if (g < M) {
        uint4 v = *(const uint4*)&chB16[row * 72 + c8 * 8];
        *(uint4*)((u16*)outv + ((size_t)(b * M + g)) * HW + pt * 64 + c8 * 8) = v;
      }
    }
  }
}

// ---------------------------------------------------------------------------
// k4: depthwise 3x3 (zero pad), LDS-staged plane + fused row l2-norm.
// ---------------------------------------------------------------------------
__global__ __launch_bounds__(256) void k4_dw(const u16* __restrict__ qp, const u16* __restrict__ kvp,
                                             const float* __restrict__ wqdw, const float* __restrict__ wkvdw,
                                             u16* __restrict__ qd, u16* __restrict__ kvd,
                                             float* __restrict__ rnq, float* __restrict__ rnk) {
  __shared__ u16 plane[16384];
  __shared__ float red[256];

  int c = blockIdx.x, b = blockIdx.y;
  int tid = threadIdx.x;
  const u16* in; u16* outb; const float* wp; int C;
  int isQ = (c < 384), cc = isQ ? c : c - 384;
  if (isQ) { in = qp; outb = qd; wp = wqdw + cc * 9; C = CDIM; }
  else     { in = kvp; outb = kvd; wp = wkvdw + cc * 9; C = KVC; }
  size_t base = ((size_t)(b * C + cc)) * HW;

  float w[9];
#pragma unroll
  for (int j = 0; j < 9; ++j) w[j] = wp[j];

  const uint4* gsrc = (const uint4*)(in + base);
  uint4* lplane = (uint4*)plane;
#pragma unroll
  for (int i = 0; i < 8; ++i) lplane[tid + i * 256] = gsrc[tid + i * 256];
  __syncthreads();

  uint4* gdst = (uint4*)(outb + base);
  float ns = 0.f;
#pragma unroll
  for (int it = 0; it < 8; ++it) {
    int idx = tid + it * 256;
    int y = idx >> 4, ox = idx & 15;
    int x0 = ox * 8;

    float r[3][10];
#pragma unroll
    for (int rr = 0; rr < 3; ++rr) {
      int yy = y + rr - 1;
      if ((unsigned)yy < 128u) {
        int rbase = yy * 128 + x0;
        r[rr][0] = (x0 > 0) ? b2f(plane[rbase - 1]) : 0.f;
        uint4 v = *(const uint4*)&plane[rbase];
        u32 ws[4] = {v.x, v.y, v.z, v.w};
#pragma unroll
        for (int j = 0; j < 4; ++j) {
          r[rr][1 + 2 * j] = b2f((u16)(ws[j] & 0xffff));
          r[rr][2 + 2 * j] = b2f((u16)(ws[j] >> 16));
        }
        r[rr][9] = (x0 < 120) ? b2f(plane[rbase + 8]) : 0.f;
      } else {
#pragma unroll
        for (int j = 0; j < 10; ++j) r[rr][j] = 0.f;
      }
    }

    u32 packed[4];
#pragma unroll
    for (int j = 0; j < 8; ++j) {
      float a = 0.f;
#pragma unroll
      for (int rr = 0; rr < 3; ++rr)
#pragma unroll
        for (int dx = 0; dx < 3; ++dx)
          a += w[rr * 3 + dx] * r[rr][j + dx];
      u16 h = f2b(a);
      float hv = b2f(h);
      ns += hv * hv;
      if (j & 1) packed[j >> 1] |= ((u32)h) << 16; else packed[j >> 1] = (u32)h;
    }
    gdst[idx] = make_uint4(packed[0], packed[1], packed[2], packed[3]);
  }

  red[tid] = ns;
  __syncthreads();
  for (int st = 128; st > 0; st >>= 1) {
    if (tid < st) red[tid] += red[tid + st];
    __syncthreads();
  }
  if (tid == 0) {
    float n = sqrtf(red[0]);
    float inv = 1.f / fmaxf(n, 1e-12f);
    if (isQ) rnq[b * 384 + cc] = inv;
    else if (cc < 96) rnk[b * 96 + cc] = inv;
  }
}

// ---------------------------------------------------------------------------
// k5b: transpose v (kvd rows 96..191) -> vt [b][p][96] via LDS.
// ---------------------------------------------------------------------------
__global__ __launch_bounds__(256) void k5b_vt(const u16* __restrict__ kvd, u16* __restrict__ vt) {
  __shared__ u16 tile[96 * 136];

  const int pt = blockIdx.x, b = blockIdx.y;
  const int tid = threadIdx.x;

#pragma unroll
  for (int i = 0; i < 6; ++i) {
    int idx = tid + i * 256;
    int row = idx >> 4, ch = idx & 15;
    uint4 v = *(const uint4*)(kvd + ((size_t)(b * KVC + 96 + row)) * HW + pt * 128 + ch * 8);
    *(uint4*)&tile[row * 136 + ch * 8] = v;
  }
  __syncthreads();

#pragma unroll
  for (int i = 0; i < 6; ++i) {
    int idx = tid + i * 256;
    int p = idx / 12, ch = idx % 12;
    u32 pk[4];
#pragma unroll
    for (int e = 0; e < 8; e += 2) {
      u16 h0 = tile[(ch * 8 + e) * 136 + p];
      u16 h1 = tile[(ch * 8 + e + 1) * 136 + p];
      pk[e >> 1] = (u32)h0 | ((u32)h1 << 16);
    }
    *(uint4*)(vt + ((size_t)(b * HW + pt * 128 + p)) * 96 + ch * 8) =
        make_uint4(pk[0], pk[1], pk[2], pk[3]);
  }
}

// ---------------------------------------------------------------------------
// k6: split-K QK^T partials. grid (8, 8, 8).
// ---------------------------------------------------------------------------
__global__ __launch_bounds__(256) void k6_qk(const u16* __restrict__ qd,
                                             const u16* __restrict__ kvd,
                                             float* __restrict__ spart) {
  int kc = blockIdx.x, h = blockIdx.y, b = blockIdx.z;
  int tid = threadIdx.x;
  int w = tid >> 6, l = tid & 63, lr = l & 15, lg = l >> 4;
  int g = h >> 2;
  int p0 = kc * 2048 + w * 512;

  f32x4 acc[3][3] = {};
  size_t qbase = ((size_t)(b * CDIM + h * 48 + lr)) * HW;
  size_t kbase = ((size_t)(b * KVC + g * 48 + lr)) * HW;

  for (int ks = 0; ks < 16; ++ks) {
    int pp = p0 + ks * 32 + lg * 8;
    s16x8 a[3], bb[3];
#pragma unroll
    for (int mi = 0; mi < 3; ++mi) a[mi] = *(const s16x8*)(qd + qbase + (size_t)mi * 16 * HW + pp);
#pragma unroll
    for (int ni = 0; ni < 3; ++ni) bb[ni] = *(const s16x8*)(kvd + kbase + (size_t)ni * 16 * HW + pp);
#pragma unroll
    for (int mi = 0; mi < 3; ++mi)
#pragma unroll
      for (int ni = 0; ni < 3; ++ni)
        acc[mi][ni] = __builtin_amdgcn_mfma_f32_16x16x32_bf16(a[mi], bb[ni], acc[mi][ni], 0, 0, 0);
  }

  size_t sb = ((size_t)((((b * 8 + h) * 8) + kc) * 4 + w)) * 2304;
#pragma unroll
  for (int mi = 0; mi < 3; ++mi)
#pragma unroll
    for (int ni = 0; ni < 3; ++ni)
#pragma unroll
      for (int r = 0; r < 4; ++r) {
        int c = mi * 16 + lg * 4 + r, d = ni * 16 + lr;
        spart[sb + c * 48 + d] = acc[mi][ni][r];
      }
}

// ---------------------------------------------------------------------------
// k7: reduce partials + scale + softmax -> P~ [b][384][96] bf16.
// ---------------------------------------------------------------------------
__global__ void k7_sm(const float* __restrict__ spart, const float* __restrict__ temp,
                      const float* __restrict__ rnq, const float* __restrict__ rnk,
                      u16* __restrict__ ptil) {
  int h = blockIdx.x, b = blockIdx.y, tid = threadIdx.x;
  int g = h >> 2;
  __shared__ float S[2304];
  size_t base = ((size_t)((b * 8 + h) * 32)) * 2304;
  for (int e = tid; e < 2304; e += 64) {
    float s = 0.f;
    for (int j = 0; j < 32; ++j) s += spart[base + (size_t)j * 2304 + e];
    S[e] = s;
  }
  __syncthreads();
  if (tid < 48) {
    int c = tid;
    float sq = temp[h] * rnq[b * 384 + h * 48 + c];
    float mx = -1e30f;
    for (int d = 0; d < 48; ++d) {
      float v = S[c * 48 + d] * sq * rnk[b * 96 + g * 48 + d];
      mx = fmaxf(mx, v);
    }
    float sum = 0.f;
    for (int d = 0; d < 48; ++d) {
      float v = S[c * 48 + d] * sq * rnk[b * 96 + g * 48 + d];
      sum += __expf(v - mx);
    }
    float inv = 1.f / sum;
    u16* row = ptil + ((size_t)(b * 384 + h * 48 + c)) * 96;
    for (int dk = 0; dk < 96; ++dk) {
      int d = dk - g * 48;
      float pv = 0.f;
      if (d >= 0 && d < 48) {
        float v = S[c * 48 + d] * sq * rnk[b * 96 + g * 48 + d];
        pv = __expf(v - mx) * inv;
      }
      row[dk] = f2b(pv);
    }
  }
}

// ---------------------------------------------------------------------------
// k8_out: fused PV + out-projection, P=128, 1024 thr (16 waves 8m x 2n).
// ---------------------------------------------------------------------------
__global__ __launch_bounds__(1024, 4) void k8_out(const u16* __restrict__ vt,
                                                  const u16* __restrict__ ptil,
                                                  const u16* __restrict__ wop,
                                                  float* __restrict__ out) {
  __shared__ __align__(16) char smem[125952];
  u16* tB = (u16*)smem;                       // 128 x 384 u16 = 96 KB
  u16* tV = (u16*)(smem + 98304);             // 128 x 104 u16 = 26624 B
  float* chB32 = (float*)smem;                // epilogue: [192][132] f32

  const int b = blockIdx.z;
  const int pt = ((blockIdx.x & 7) << 4) | (blockIdx.x >> 3);   // 128=8x16 bijective
  const int tid = threadIdx.x;
  const int w = tid >> 6, l = tid & 63;
  const int wm = w >> 1, wn = w & 1;
  const int lr = l & 15, lg = l >> 4;

  // ---- stage vt tile: 128 rows x 12 chunks = 1536 uint4
  {
#pragma unroll
    for (int i = 0; i < 2; ++i) {
      int c0 = tid + i * 1024;
      if (c0 < 1536) {
        int row = c0 / 12, cc = c0 % 12;
        uint4 v = *(const uint4*)(vt + ((size_t)(b * HW + pt * 128 + row)) * 96 + cc * 8);
        *(uint4*)&tV[row * 104 + cc * 8] = v;
      }
    }
  }
  __syncthreads();

  // ---- Phase A: Yt = ptil x vt^T
  {
    f32x4 accA[3][4] = {};
#pragma unroll
    for (int ks = 0; ks < 3; ++ks) {
      s16x8 a[3], bb[4];
#pragma unroll
      for (int mf = 0; mf < 3; ++mf)
        a[mf] = *(const s16x8*)(ptil + ((size_t)(b * 384 + wm * 48 + mf * 16 + lr)) * 96 + ks * 32 + lg * 8);
#pragma unroll
      for (int nf = 0; nf < 4; ++nf)
        bb[nf] = *(const s16x8*)&tV[(wn * 64 + nf * 16 + lr) * 104 + ks * 32 + lg * 8];
#pragma unroll
      for (int mf = 0; mf < 3; ++mf)
#pragma unroll
        for (int nf = 0; nf < 4; ++nf)
          accA[mf][nf] = __builtin_amdgcn_mfma_f32_16x16x32_bf16(a[mf], bb[nf], accA[mf][nf], 0, 0, 0);
    }
#pragma unroll
    for (int mf = 0; mf < 3; ++mf)
#pragma unroll
      for (int nf = 0; nf < 4; ++nf) {
        int prow = wn * 64 + nf * 16 + lr;
        int cbase = wm * 48 + mf * 16 + lg * 4;
        u32 lo = pack2(accA[mf][nf][0], accA[mf][nf][1]);
        u32 hi = pack2(accA[mf][nf][2], accA[mf][nf][3]);
        int chunk = (cbase >> 3) ^ ((prow >> 1) & 7);
        int off = prow * 384 + chunk * 8 + (cbase & 7);
        *(uint2*)&tB[off] = make_uint2(lo, hi);
      }
  }
  __syncthreads();

  // ---- Phase B: out = wop x tB (K=384), ping-pong prefetch
  f32x4 acc[3][4] = {};
  {
    s16x8 a[2][3], bb[2][4];
#pragma unroll
    for (int mf = 0; mf < 3; ++mf)
      a[0][mf] = *(const s16x8*)(wop + (size_t)(wm * 48 + mf * 16 + lr) * 384 + lg * 8);
#pragma unroll
    for (int nf = 0; nf < 4; ++nf) {
      int row = wn * 64 + nf * 16 + lr;
      bb[0][nf] = *(const s16x8*)&tB[row * 384 + ((lg ^ ((row >> 1) & 7)) << 3)];
    }
#pragma unroll
    for (int ks = 0; ks < 12; ++ks) {
      const int cur = ks & 1, nxt = cur ^ 1;
      if (ks < 11) {
        const int ko = (ks + 1) * 32 + lg * 8;
        const int cidx = (ks + 1) * 4 + lg;
#pragma unroll
        for (int mf = 0; mf < 3; ++mf)
          a[nxt][mf] = *(const s16x8*)(wop + (size_t)(wm * 48 + mf * 16 + lr) * 384 + ko);
#pragma unroll
        for (int nf = 0; nf < 4; ++nf) {
          int row = wn * 64 + nf * 16 + lr;
          bb[nxt][nf] = *(const s16x8*)&tB[row * 384 + ((cidx ^ ((row >> 1) & 7)) << 3)];
        }
      }
#pragma unroll
      for (int mf = 0; mf < 3; ++mf)
#pragma unroll
        for (int nf = 0; nf < 4; ++nf)
          acc[mf][nf] = __builtin_amdgcn_mfma_f32_16x16x32_bf16(a[cur][mf], bb[cur][nf], acc[mf][nf], 0, 0, 0);
    }
  }

  // ---- Epilogue: f32 NCHW via LDS transpose, 2 chunks of 192 o-rows
#pragma unroll
  for (int cc = 0; cc < 2; ++cc) {
    __syncthreads();
    if ((wm >> 2) == cc) {
#pragma unroll
      for (int nf = 0; nf < 4; ++nf) {
        int prow = wn * 64 + nf * 16 + lr;
#pragma unroll
        for (int mf = 0; mf < 3; ++mf)
#pragma unroll
          for (int r = 0; r < 4; ++r) {
            int orow_l = (wm & 3) * 48 + mf * 16 + lg * 4 + r;
            chB32[orow_l * 132 + prow] = acc[mf][nf][r];
          }
      }
    }
    __syncthreads();
    for (int i = tid; i < 192 * 32; i += 1024) {
      int row = i >> 5, c4 = i & 31;
      uint4 v = *(const uint4*)&chB32[row * 132 + c4 * 4];
      *(uint4*)(out + ((size_t)(b * CDIM + cc * 192 + row)) * HW + pt * 128 + c4 * 4) = v;
    }
  }
}

// ---------------------------------------------------------------------------
extern "C" void kernel_launch(void* const* d_in, const int* in_sizes, int n_in,
                              void* d_out, int out_size, void* d_ws, size_t ws_size,
                              hipStream_t stream) {
  const float* q    = (const float*)d_in[0];
  const float* k    = (const float*)d_in[1];
  const float* w_q  = (const float*)d_in[2];
  const float* w_kv = (const float*)d_in[3];
  const float* w_qd = (const float*)d_in[4];
  const float* w_kd = (const float*)d_in[5];
  const float* w_o  = (const float*)d_in[6];
  const float* temp = (const float*)d_in[7];
  const float* lnqw = (const float*)d_in[8];
  const float* lnqb = (const float*)d_in[9];
  const float* lnkw = (const float*)d_in[10];
  const float* lnkb = (const float*)d_in[11];
  float* out = (float*)d_out;

  char* ws = (char*)d_ws;
  size_t off = 0;
  auto alloc = [&](size_t bytes) -> void* {
    void* p = ws + off;
    off += (bytes + 255) & ~(size_t)255;
    return p;
  };

  u16*   wqp   = (u16*)alloc(384 * 384 * 2);
  float* rwsQ  = (float*)alloc(384 * 4);
  float* biasQ = (float*)alloc(384 * 4);
  u16*   wkvp  = (u16*)alloc(384 * 384 * 2);   // zero-padded to 384 rows
  float* rwsKV = (float*)alloc(384 * 4);
  float* biasKV= (float*)alloc(384 * 4);
  u16*   wop   = (u16*)alloc(384 * 384 * 2);
  u16*   qp    = (u16*)alloc((size_t)NB * CDIM * HW * 2);
  u16*   kvp   = (u16*)alloc((size_t)NB * KVC * HW * 2);
  u16*   qd    = (u16*)alloc((size_t)NB * CDIM * HW * 2);
  u16*   kvd   = (u16*)alloc((size_t)NB * KVC * HW * 2);
  u16*   vt    = (u16*)alloc((size_t)NB * HW * 96 * 2);
  float* spart = (float*)alloc((size_t)2048 * 2304 * 4);
  u16*   ptil  = (u16*)alloc((size_t)NB * CDIM * 96 * 2);
  float* rnq   = (float*)alloc((size_t)NB * 384 * 4);
  float* rnk   = (float*)alloc((size_t)NB * 96 * 4);

  k0_prep<<<5, 256, 0, stream>>>(w_q, w_kv, w_o, lnqw, lnqb, lnkw, lnkb,
                                 wqp, rwsQ, biasQ, wkvp, rwsKV, biasKV, wop);

  gemm_fused<0, 8, 1, 3, 4><<<dim3(256, 1, NB), 512, 0, stream>>>(wqp, q, rwsQ, biasQ, qp, 384);
  gemm_fused<0, 4, 2, 3, 2><<<dim3(256, 1, NB), 512, 0, stream>>>(wkvp, k, rwsKV, biasKV, kvp, 192);

  k4_dw<<<dim3(576, NB), 256, 0, stream>>>(qp, kvp, w_qd, w_kd, qd, kvd, rnq, rnk);

  k5b_vt<<<dim3(128, NB), 256, 0, stream>>>(kvd, vt);

  k6_qk<<<dim3(8, 8, NB), 256, 0, stream>>>(qd, kvd, spart);
  k7_sm<<<dim3(8, NB), 64, 0, stream>>>(spart, temp, rnq, rnk, ptil);

  k8_out<<<dim3(128, 1, NB), 1024, 0, stream>>>(vt, ptil, wop, out);
}

// Round 19
// 540.293 us; speedup vs baseline: 1.0155x; 1.0155x over previous
//
#include <hip/hip_runtime.h>
#include <math.h>

// ---------------------------------------------------------------------------
// CrossGroupedQueryAttention on MI355X — round 19 (lock-in of R17 best, 540us)
//
// R18 post-mortem: reg-pipelined staging + 52KB LDS = within-noise negative
// (548.7 vs 540.7). Decision rule fired: projection floor (~163us, ~1.25TB/s)
// confirmed robust against the complete lever set (8 structures, vmcnt
// pipelines, producer/consumer, gll-direct, register depth x3, segment width
// 256/512/1024B, LDS sizing, XCD swizzles, dispatch merging). Structural
// constraint: NCHW-f32 gather at 64KB plane stride = page-transition-bound;
// remaining fixes require measured-failed prerequisites (R8 spill, R9 L3
// re-read, R16 segment width) or upstream layout changes (two-pass transpose
// = break-even arithmetic).
// R19 = byte-exact revert to the measured best (R17). Expect ~540us.
// ---------------------------------------------------------------------------

typedef unsigned short u16;
typedef unsigned int u32;
typedef short s16x8 __attribute__((ext_vector_type(8)));
typedef float f32x4 __attribute__((ext_vector_type(4)));

#define HW 16384
#define NB 8
#define CDIM 384
#define KVC 192

__device__ __forceinline__ float b2f(u16 u) {
  return __uint_as_float(((u32)u) << 16);
}
__device__ __forceinline__ u16 f2b(float f) {
  u32 u = __float_as_uint(f);
  u += 0x7fffu + ((u >> 16) & 1u);   // RNE
  return (u16)(u >> 16);
}
__device__ __forceinline__ u32 pack2(float a, float c) {
  return (u32)f2b(a) | ((u32)f2b(c) << 16);
}

// ---------------------------------------------------------------------------
// k0: fold LN weights. 5 blocks x 256. wkvp zero-padded to 384 rows.
// ---------------------------------------------------------------------------
__global__ void k0_prep(const float* __restrict__ wq, const float* __restrict__ wkv,
                        const float* __restrict__ wo,
                        const float* __restrict__ lnqw, const float* __restrict__ lnqb,
                        const float* __restrict__ lnkw, const float* __restrict__ lnkb,
                        u16* __restrict__ wqp, float* __restrict__ rwsQ, float* __restrict__ biasQ,
                        u16* __restrict__ wkvp, float* __restrict__ rwsKV, float* __restrict__ biasKV,
                        u16* __restrict__ wop) {
  int r = blockIdx.x * 256 + threadIdx.x;
  if (r < 384) {
    float rs = 0.f, bs = 0.f;
    for (int i = 0; i < 384; ++i) {
      float wp = wq[r * 384 + i] * lnqw[i];
      u16 h = f2b(wp);
      rs += b2f(h);
      bs += wq[r * 384 + i] * lnqb[i];
      wqp[r * 384 + i] = h;
    }
    rwsQ[r] = rs; biasQ[r] = bs;
  } else if (r < 768) {
    int o = r - 384;
    if (o < 192) {
      float rs = 0.f, bs = 0.f;
      for (int i = 0; i < 384; ++i) {
        float wp = wkv[o * 384 + i] * lnkw[i];
        u16 h = f2b(wp);
        rs += b2f(h);
        bs += wkv[o * 384 + i] * lnkb[i];
        wkvp[o * 384 + i] = h;
      }
      rwsKV[o] = rs; biasKV[o] = bs;
    } else {
      for (int i = 0; i < 384; ++i) wkvp[o * 384 + i] = 0;
      rwsKV[o] = 0.f; biasKV[o] = 0.f;
    }
  } else if (r < 1152) {
    int o = r - 768;
    for (int i = 0; i < 384; ++i) wop[o * 384 + i] = f2b(wo[o * 384 + i]);
  }
}

// ---------------------------------------------------------------------------
// gemm_fused (R12/R15-proven): D[o][p]=sum_k A[o][k]*B[p][k], K=384,
// tile M x 64px, 512 thr. Phase1 batched 48-load B-stage -> 48KB swizzled
// LDS + stats; one barrier; phase2 A direct from L2 ping-pong; epilogue
// LN + LDS transpose (128B segments).
// ---------------------------------------------------------------------------
template <int MODE, int WM, int WN, int MF, int NF>
__global__ __launch_bounds__(512, 4) void gemm_fused(const u16* __restrict__ A,
                                                     const void* __restrict__ Bsrc,
                                                     const float* __restrict__ rowsum,
                                                     const float* __restrict__ bias,
                                                     void* __restrict__ outv, int M) {
  __shared__ __align__(16) char smem[57344];
  u16*   tB    = (u16*)smem;                  // 64 x 384 u16 = 48 KB
  float* sredS = (float*)(smem + 49152);      // [8][64]
  float* sredQ = (float*)(smem + 53248);      // [8][64]
  u16*   chB16 = (u16*)smem;                  // epilogue: [M_TILE][72] u16
  __shared__ float muL[64], sdL[64];

  constexpr int M_TILE = WM * MF * 16;

  const int b = blockIdx.z;
  const int pt = ((blockIdx.x & 7) << 5) | (blockIdx.x >> 3);   // XCD-bijective
  const int tid = threadIdx.x;
  const int w = tid >> 6, l = tid & 63;
  const int wm = (WN == 1) ? w : (w >> 1);
  const int wn = (WN == 1) ? 0 : (w & 1);
  const int lr = l & 15, lg = l >> 4;

  f32x4 acc[MF][NF] = {};

  // Phase 1: stage B panel (batched loads)
  {
    const float* Bf = (const float*)Bsrc;
    const size_t fbase = (size_t)b * CDIM * HW + (size_t)pt * 64 + l;  // lane=px
    float v[48];
#pragma unroll
    for (int it = 0; it < 12; ++it)
#pragma unroll
      for (int j = 0; j < 4; ++j)
        v[it * 4 + j] = Bf[fbase + (size_t)(it * 32 + w * 4 + j) * HW];

    float s_ = 0.f, q_ = 0.f;
#pragma unroll
    for (int it = 0; it < 12; ++it) {
      float v0 = v[it * 4], v1 = v[it * 4 + 1], v2 = v[it * 4 + 2], v3 = v[it * 4 + 3];
      s_ += (v0 + v1) + (v2 + v3);
      q_ += (v0 * v0 + v1 * v1) + (v2 * v2 + v3 * v3);
      u32 lo = pack2(v0, v1), hi = pack2(v2, v3);
      int cidx = it * 4 + (w >> 1);
      int off = l * 384 + ((cidx ^ (l & 7)) << 3) + (w & 1) * 4;
      *(uint2*)&tB[off] = make_uint2(lo, hi);
    }
    sredS[w * 64 + l] = s_;
    sredQ[w * 64 + l] = q_;
  }
  __syncthreads();

  if (tid < 64) {
    float s = 0.f, q2 = 0.f;
#pragma unroll
    for (int g = 0; g < 8; ++g) { s += sredS[g * 64 + tid]; q2 += sredQ[g * 64 + tid]; }
    float mn = s * (1.f / 384.f);
    float var = q2 * (1.f / 384.f) - mn * mn;
    muL[tid] = mn;
    sdL[tid] = rsqrtf(var + 1e-5f);
  }
  __syncthreads();

  // Phase 2: MFMA, ping-pong prefetch
  s16x8 a[2][MF], bb[2][NF];
#pragma unroll
  for (int mf = 0; mf < MF; ++mf)
    a[0][mf] = *(const s16x8*)(A + (size_t)(wm * (MF * 16) + mf * 16 + lr) * 384 + lg * 8);
#pragma unroll
  for (int nf = 0; nf < NF; ++nf) {
    int row = wn * (NF * 16) + nf * 16 + lr;
    bb[0][nf] = *(const s16x8*)&tB[row * 384 + ((lg ^ (row & 7)) << 3)];
  }
#pragma unroll
  for (int ks = 0; ks < 12; ++ks) {
    const int cur = ks & 1, nxt = cur ^ 1;
    if (ks < 11) {
      const int ko = (ks + 1) * 32 + lg * 8;
      const int cidx = (ks + 1) * 4 + lg;
#pragma unroll
      for (int mf = 0; mf < MF; ++mf)
        a[nxt][mf] = *(const s16x8*)(A + (size_t)(wm * (MF * 16) + mf * 16 + lr) * 384 + ko);
#pragma unroll
      for (int nf = 0; nf < NF; ++nf) {
        int row = wn * (NF * 16) + nf * 16 + lr;
        bb[nxt][nf] = *(const s16x8*)&tB[row * 384 + ((cidx ^ (row & 7)) << 3)];
      }
    }
#pragma unroll
    for (int mf = 0; mf < MF; ++mf)
#pragma unroll
      for (int nf = 0; nf < NF; ++nf)
        acc[mf][nf] = __builtin_amdgcn_mfma_f32_16x16x32_bf16(a[cur][mf], bb[cur][nf], acc[mf][nf], 0, 0, 0);
  }

  // Epilogue: LN + LDS transpose -> 128B-segment stores
  __syncthreads();
#pragma unroll
  for (int nf = 0; nf < NF; ++nf) {
    int prow = wn * (NF * 16) + nf * 16 + lr;
    float m_ = muL[prow], s_ = sdL[prow];
#pragma unroll
    for (int mf = 0; mf < MF; ++mf)
#pragma unroll
      for (int r = 0; r < 4; ++r) {
        int orow = wm * (MF * 16) + mf * 16 + lg * 4 + r;
        float v = s_ * (acc[mf][nf][r] - m_ * rowsum[orow]) + bias[orow];
        chB16[orow * 72 + prow] = f2b(v);
      }
  }
  __syncthreads();
  const int total = M_TILE * 8;
  for (int i = tid; i < total; i += 512) {
    int row = i >> 3, c8 = i & 7;
    if (row < M) {
      uint4 v = *(const uint4*)&chB16[row * 72 + c8 * 8];
      *(uint4*)((u16*)outv + ((size_t)(b * M + row)) * HW + pt * 64 + c8 * 8) = v;
    }
  }
}

// ---------------------------------------------------------------------------
// k4: depthwise 3x3 (zero pad), LDS-staged plane + fused row l2-norm.
// ---------------------------------------------------------------------------
__global__ __launch_bounds__(256) void k4_dw(const u16* __restrict__ qp, const u16* __restrict__ kvp,
                                             const float* __restrict__ wqdw, const float* __restrict__ wkvdw,
                                             u16* __restrict__ qd, u16* __restrict__ kvd,
                                             float* __restrict__ rnq, float* __restrict__ rnk) {
  __shared__ u16 plane[16384];
  __shared__ float red[256];

  int c = blockIdx.x, b = blockIdx.y;
  int tid = threadIdx.x;
  const u16* in; u16* outb; const float* wp; int C;
  int isQ = (c < 384), cc = isQ ? c : c - 384;
  if (isQ) { in = qp; outb = qd; wp = wqdw + cc * 9; C = CDIM; }
  else     { in = kvp; outb = kvd; wp = wkvdw + cc * 9; C = KVC; }
  size_t base = ((size_t)(b * C + cc)) * HW;

  float w[9];
#pragma unroll
  for (int j = 0; j < 9; ++j) w[j] = wp[j];

  const uint4* gsrc = (const uint4*)(in + base);
  uint4* lplane = (uint4*)plane;
#pragma unroll
  for (int i = 0; i < 8; ++i) lplane[tid + i * 256] = gsrc[tid + i * 256];
  __syncthreads();

  uint4* gdst = (uint4*)(outb + base);
  float ns = 0.f;
#pragma unroll
  for (int it = 0; it < 8; ++it) {
    int idx = tid + it * 256;
    int y = idx >> 4, ox = idx & 15;
    int x0 = ox * 8;

    float r[3][10];
#pragma unroll
    for (int rr = 0; rr < 3; ++rr) {
      int yy = y + rr - 1;
      if ((unsigned)yy < 128u) {
        int rbase = yy * 128 + x0;
        r[rr][0] = (x0 > 0) ? b2f(plane[rbase - 1]) : 0.f;
        uint4 v = *(const uint4*)&plane[rbase];
        u32 ws[4] = {v.x, v.y, v.z, v.w};
#pragma unroll
        for (int j = 0; j < 4; ++j) {
          r[rr][1 + 2 * j] = b2f((u16)(ws[j] & 0xffff));
          r[rr][2 + 2 * j] = b2f((u16)(ws[j] >> 16));
        }
        r[rr][9] = (x0 < 120) ? b2f(plane[rbase + 8]) : 0.f;
      } else {
#pragma unroll
        for (int j = 0; j < 10; ++j) r[rr][j] = 0.f;
      }
    }

    u32 packed[4];
#pragma unroll
    for (int j = 0; j < 8; ++j) {
      float a = 0.f;
#pragma unroll
      for (int rr = 0; rr < 3; ++rr)
#pragma unroll
        for (int dx = 0; dx < 3; ++dx)
          a += w[rr * 3 + dx] * r[rr][j + dx];
      u16 h = f2b(a);
      float hv = b2f(h);
      ns += hv * hv;
      if (j & 1) packed[j >> 1] |= ((u32)h) << 16; else packed[j >> 1] = (u32)h;
    }
    gdst[idx] = make_uint4(packed[0], packed[1], packed[2], packed[3]);
  }

  red[tid] = ns;
  __syncthreads();
  for (int st = 128; st > 0; st >>= 1) {
    if (tid < st) red[tid] += red[tid + st];
    __syncthreads();
  }
  if (tid == 0) {
    float n = sqrtf(red[0]);
    float inv = 1.f / fmaxf(n, 1e-12f);
    if (isQ) rnq[b * 384 + cc] = inv;
    else if (cc < 96) rnk[b * 96 + cc] = inv;
  }
}

// ---------------------------------------------------------------------------
// k5b: transpose v (kvd rows 96..191) -> vt [b][p][96] via LDS.
// grid (128, 8), 256 thr. Reads: 256B/instr coalesced rows; writes: block's
// 128 rows x 192B = 24KB contiguous, 1KB per wave-instruction.
// ---------------------------------------------------------------------------
__global__ __launch_bounds__(256) void k5b_vt(const u16* __restrict__ kvd, u16* __restrict__ vt) {
  __shared__ u16 tile[96 * 136];   // pad 136 -> transpose-read conflicts spread

  const int pt = blockIdx.x, b = blockIdx.y;
  const int tid = threadIdx.x;

  // stage: 96 ch rows x 16 uint4 (128 px) = 1536 uint4
#pragma unroll
  for (int i = 0; i < 6; ++i) {
    int idx = tid + i * 256;
    int row = idx >> 4, ch = idx & 15;
    uint4 v = *(const uint4*)(kvd + ((size_t)(b * KVC + 96 + row)) * HW + pt * 128 + ch * 8);
    *(uint4*)&tile[row * 136 + ch * 8] = v;
  }
  __syncthreads();

  // emit: 128 px rows x 12 uint4 (96 ch) = 1536 uint4, contiguous output
#pragma unroll
  for (int i = 0; i < 6; ++i) {
    int idx = tid + i * 256;
    int p = idx / 12, ch = idx % 12;
    u32 pk[4];
#pragma unroll
    for (int e = 0; e < 8; e += 2) {
      u16 h0 = tile[(ch * 8 + e) * 136 + p];
      u16 h1 = tile[(ch * 8 + e + 1) * 136 + p];
      pk[e >> 1] = (u32)h0 | ((u32)h1 << 16);
    }
    *(uint4*)(vt + ((size_t)(b * HW + pt * 128 + p)) * 96 + ch * 8) =
        make_uint4(pk[0], pk[1], pk[2], pk[3]);
  }
}

// ---------------------------------------------------------------------------
// k6: split-K QK^T partials. grid (8, 8, 8).
// ---------------------------------------------------------------------------
__global__ __launch_bounds__(256) void k6_qk(const u16* __restrict__ qd,
                                             const u16* __restrict__ kvd,
                                             float* __restrict__ spart) {
  int kc = blockIdx.x, h = blockIdx.y, b = blockIdx.z;
  int tid = threadIdx.x;
  int w = tid >> 6, l = tid & 63, lr = l & 15, lg = l >> 4;
  int g = h >> 2;
  int p0 = kc * 2048 + w * 512;

  f32x4 acc[3][3] = {};
  size_t qbase = ((size_t)(b * CDIM + h * 48 + lr)) * HW;
  size_t kbase = ((size_t)(b * KVC + g * 48 + lr)) * HW;

  for (int ks = 0; ks < 16; ++ks) {
    int pp = p0 + ks * 32 + lg * 8;
    s16x8 a[3], bb[3];
#pragma unroll
    for (int mi = 0; mi < 3; ++mi) a[mi] = *(const s16x8*)(qd + qbase + (size_t)mi * 16 * HW + pp);
#pragma unroll
    for (int ni = 0; ni < 3; ++ni) bb[ni] = *(const s16x8*)(kvd + kbase + (size_t)ni * 16 * HW + pp);
#pragma unroll
    for (int mi = 0; mi < 3; ++mi)
#pragma unroll
      for (int ni = 0; ni < 3; ++ni)
        acc[mi][ni] = __builtin_amdgcn_mfma_f32_16x16x32_bf16(a[mi], bb[ni], acc[mi][ni], 0, 0, 0);
  }

  size_t sb = ((size_t)((((b * 8 + h) * 8) + kc) * 4 + w)) * 2304;
#pragma unroll
  for (int mi = 0; mi < 3; ++mi)
#pragma unroll
    for (int ni = 0; ni < 3; ++ni)
#pragma unroll
      for (int r = 0; r < 4; ++r) {
        int c = mi * 16 + lg * 4 + r, d = ni * 16 + lr;
        spart[sb + c * 48 + d] = acc[mi][ni][r];
      }
}

// ---------------------------------------------------------------------------
// k7: reduce partials + scale + softmax -> P~ [b][384][96] bf16.
// ---------------------------------------------------------------------------
__global__ void k7_sm(const float* __restrict__ spart, const float* __restrict__ temp,
                      const float* __restrict__ rnq, const float* __restrict__ rnk,
                      u16* __restrict__ ptil) {
  int h = blockIdx.x, b = blockIdx.y, tid = threadIdx.x;
  int g = h >> 2;
  __shared__ float S[2304];
  size_t base = ((size_t)((b * 8 + h) * 32)) * 2304;
  for (int e = tid; e < 2304; e += 64) {
    float s = 0.f;
    for (int j = 0; j < 32; ++j) s += spart[base + (size_t)j * 2304 + e];
    S[e] = s;
  }
  __syncthreads();
  if (tid < 48) {
    int c = tid;
    float sq = temp[h] * rnq[b * 384 + h * 48 + c];
    float mx = -1e30f;
    for (int d = 0; d < 48; ++d) {
      float v = S[c * 48 + d] * sq * rnk[b * 96 + g * 48 + d];
      mx = fmaxf(mx, v);
    }
    float sum = 0.f;
    for (int d = 0; d < 48; ++d) {
      float v = S[c * 48 + d] * sq * rnk[b * 96 + g * 48 + d];
      sum += __expf(v - mx);
    }
    float inv = 1.f / sum;
    u16* row = ptil + ((size_t)(b * 384 + h * 48 + c)) * 96;
    for (int dk = 0; dk < 96; ++dk) {
      int d = dk - g * 48;
      float pv = 0.f;
      if (d >= 0 && d < 48) {
        float v = S[c * 48 + d] * sq * rnk[b * 96 + g * 48 + d];
        pv = __expf(v - mx) * inv;
      }
      row[dk] = f2b(pv);
    }
  }
}

// ---------------------------------------------------------------------------
// k8_out: fused PV + out-projection, P=128, 1024 thr (16 waves 8m x 2n).
// ---------------------------------------------------------------------------
__global__ __launch_bounds__(1024, 4) void k8_out(const u16* __restrict__ vt,
                                                  const u16* __restrict__ ptil,
                                                  const u16* __restrict__ wop,
                                                  float* __restrict__ out) {
  __shared__ __align__(16) char smem[125952];
  u16* tB = (u16*)smem;                       // 128 x 384 u16 = 96 KB
  u16* tV = (u16*)(smem + 98304);             // 128 x 104 u16 = 26624 B
  float* chB32 = (float*)smem;                // epilogue: [192][132] f32

  const int b = blockIdx.z;
  const int pt = ((blockIdx.x & 7) << 4) | (blockIdx.x >> 3);   // 128=8x16 bijective
  const int tid = threadIdx.x;
  const int w = tid >> 6, l = tid & 63;
  const int wm = w >> 1, wn = w & 1;
  const int lr = l & 15, lg = l >> 4;

  // ---- stage vt tile: 128 rows x 12 chunks = 1536 uint4
  {
#pragma unroll
    for (int i = 0; i < 2; ++i) {
      int c0 = tid + i * 1024;
      if (c0 < 1536) {
        int row = c0 / 12, cc = c0 % 12;
        uint4 v = *(const uint4*)(vt + ((size_t)(b * HW + pt * 128 + row)) * 96 + cc * 8);
        *(uint4*)&tV[row * 104 + cc * 8] = v;
      }
    }
  }
  __syncthreads();

  // ---- Phase A: Yt = ptil x vt^T
  {
    f32x4 accA[3][4] = {};
#pragma unroll
    for (int ks = 0; ks < 3; ++ks) {
      s16x8 a[3], bb[4];
#pragma unroll
      for (int mf = 0; mf < 3; ++mf)
        a[mf] = *(const s16x8*)(ptil + ((size_t)(b * 384 + wm * 48 + mf * 16 + lr)) * 96 + ks * 32 + lg * 8);
#pragma unroll
      for (int nf = 0; nf < 4; ++nf)
        bb[nf] = *(const s16x8*)&tV[(wn * 64 + nf * 16 + lr) * 104 + ks * 32 + lg * 8];
#pragma unroll
      for (int mf = 0; mf < 3; ++mf)
#pragma unroll
        for (int nf = 0; nf < 4; ++nf)
          accA[mf][nf] = __builtin_amdgcn_mfma_f32_16x16x32_bf16(a[mf], bb[nf], accA[mf][nf], 0, 0, 0);
    }
#pragma unroll
    for (int mf = 0; mf < 3; ++mf)
#pragma unroll
      for (int nf = 0; nf < 4; ++nf) {
        int prow = wn * 64 + nf * 16 + lr;
        int cbase = wm * 48 + mf * 16 + lg * 4;
        u32 lo = pack2(accA[mf][nf][0], accA[mf][nf][1]);
        u32 hi = pack2(accA[mf][nf][2], accA[mf][nf][3]);
        int chunk = (cbase >> 3) ^ ((prow >> 1) & 7);
        int off = prow * 384 + chunk * 8 + (cbase & 7);
        *(uint2*)&tB[off] = make_uint2(lo, hi);
      }
  }
  __syncthreads();

  // ---- Phase B: out = wop x tB (K=384), ping-pong prefetch
  f32x4 acc[3][4] = {};
  {
    s16x8 a[2][3], bb[2][4];
#pragma unroll
    for (int mf = 0; mf < 3; ++mf)
      a[0][mf] = *(const s16x8*)(wop + (size_t)(wm * 48 + mf * 16 + lr) * 384 + lg * 8);
#pragma unroll
    for (int nf = 0; nf < 4; ++nf) {
      int row = wn * 64 + nf * 16 + lr;
      bb[0][nf] = *(const s16x8*)&tB[row * 384 + ((lg ^ ((row >> 1) & 7)) << 3)];
    }
#pragma unroll
    for (int ks = 0; ks < 12; ++ks) {
      const int cur = ks & 1, nxt = cur ^ 1;
      if (ks < 11) {
        const int ko = (ks + 1) * 32 + lg * 8;
        const int cidx = (ks + 1) * 4 + lg;
#pragma unroll
        for (int mf = 0; mf < 3; ++mf)
          a[nxt][mf] = *(const s16x8*)(wop + (size_t)(wm * 48 + mf * 16 + lr) * 384 + ko);
#pragma unroll
        for (int nf = 0; nf < 4; ++nf) {
          int row = wn * 64 + nf * 16 + lr;
          bb[nxt][nf] = *(const s16x8*)&tB[row * 384 + ((cidx ^ ((row >> 1) & 7)) << 3)];
        }
      }
#pragma unroll
      for (int mf = 0; mf < 3; ++mf)
#pragma unroll
        for (int nf = 0; nf < 4; ++nf)
          acc[mf][nf] = __builtin_amdgcn_mfma_f32_16x16x32_bf16(a[cur][mf], bb[cur][nf], acc[mf][nf], 0, 0, 0);
    }
  }

  // ---- Epilogue: f32 NCHW via LDS transpose, 2 chunks of 192 o-rows
#pragma unroll
  for (int cc = 0; cc < 2; ++cc) {
    __syncthreads();
    if ((wm >> 2) == cc) {
#pragma unroll
      for (int nf = 0; nf < 4; ++nf) {
        int prow = wn * 64 + nf * 16 + lr;
#pragma unroll
        for (int mf = 0; mf < 3; ++mf)
#pragma unroll
          for (int r = 0; r < 4; ++r) {
            int orow_l = (wm & 3) * 48 + mf * 16 + lg * 4 + r;
            chB32[orow_l * 132 + prow] = acc[mf][nf][r];
          }
      }
    }
    __syncthreads();
    for (int i = tid; i < 192 * 32; i += 1024) {
      int row = i >> 5, c4 = i & 31;
      uint4 v = *(const uint4*)&chB32[row * 132 + c4 * 4];
      *(uint4*)(out + ((size_t)(b * CDIM + cc * 192 + row)) * HW + pt * 128 + c4 * 4) = v;
    }
  }
}

// ---------------------------------------------------------------------------
extern "C" void kernel_launch(void* const* d_in, const int* in_sizes, int n_in,
                              void* d_out, int out_size, void* d_ws, size_t ws_size,
                              hipStream_t stream) {
  const float* q    = (const float*)d_in[0];
  const float* k    = (const float*)d_in[1];
  const float* w_q  = (const float*)d_in[2];
  const float* w_kv = (const float*)d_in[3];
  const float* w_qd = (const float*)d_in[4];
  const float* w_kd = (const float*)d_in[5];
  const float* w_o  = (const float*)d_in[6];
  const float* temp = (const float*)d_in[7];
  const float* lnqw = (const float*)d_in[8];
  const float* lnqb = (const float*)d_in[9];
  const float* lnkw = (const float*)d_in[10];
  const float* lnkb = (const float*)d_in[11];
  float* out = (float*)d_out;

  char* ws = (char*)d_ws;
  size_t off = 0;
  auto alloc = [&](size_t bytes) -> void* {
    void* p = ws + off;
    off += (bytes + 255) & ~(size_t)255;
    return p;
  };

  u16*   wqp   = (u16*)alloc(384 * 384 * 2);
  float* rwsQ  = (float*)alloc(384 * 4);
  float* biasQ = (float*)alloc(384 * 4);
  u16*   wkvp  = (u16*)alloc(384 * 384 * 2);   // zero-padded to 384 rows
  float* rwsKV = (float*)alloc(384 * 4);
  float* biasKV= (float*)alloc(384 * 4);
  u16*   wop   = (u16*)alloc(384 * 384 * 2);
  u16*   qp    = (u16*)alloc((size_t)NB * CDIM * HW * 2);
  u16*   kvp   = (u16*)alloc((size_t)NB * KVC * HW * 2);
  u16*   qd    = (u16*)alloc((size_t)NB * CDIM * HW * 2);
  u16*   kvd   = (u16*)alloc((size_t)NB * KVC * HW * 2);
  u16*   vt    = (u16*)alloc((size_t)NB * HW * 96 * 2);
  float* spart = (float*)alloc((size_t)2048 * 2304 * 4);
  u16*   ptil  = (u16*)alloc((size_t)NB * CDIM * 96 * 2);
  float* rnq   = (float*)alloc((size_t)NB * 384 * 4);
  float* rnk   = (float*)alloc((size_t)NB * 96 * 4);

  k0_prep<<<5, 256, 0, stream>>>(w_q, w_kv, w_o, lnqw, lnqb, lnkw, lnkb,
                                 wqp, rwsQ, biasQ, wkvp, rwsKV, biasKV, wop);

  gemm_fused<0, 8, 1, 3, 4><<<dim3(256, 1, NB), 512, 0, stream>>>(wqp, q, rwsQ, biasQ, qp, 384);
  gemm_fused<0, 4, 2, 3, 2><<<dim3(256, 1, NB), 512, 0, stream>>>(wkvp, k, rwsKV, biasKV, kvp, 192);

  k4_dw<<<dim3(576, NB), 256, 0, stream>>>(qp, kvp, w_qd, w_kd, qd, kvd, rnq, rnk);

  k5b_vt<<<dim3(128, NB), 256, 0, stream>>>(kvd, vt);

  k6_qk<<<dim3(8, 8, NB), 256, 0, stream>>>(qd, kvd, spart);
  k7_sm<<<dim3(8, NB), 64, 0, stream>>>(spart, temp, rnq, rnk, ptil);

  k8_out<<<dim3(128, 1, NB), 1024, 0, stream>>>(vt, ptil, wop, out);
}